// Round 3
// baseline (307.706 us; speedup 1.0000x reference)
//
#include <hip/hip_runtime.h>
#include <math.h>

#define B_ 16
#define T_ 6000
#define F_ 257
#define M_ 64
#define R_ (B_*T_)          // 96000 flat rows

// scan chunking
#define CHUNKS 48
#define CLEN   (T_/CHUNKS)  // 125
#define WARM   96           // worst-case decay 0.726^96 ~ 5e-14 -> below fp32 noise

#define MAXSUP 32
#define TILE_R 32
#define TILE_E (TILE_R*F_)  // 8224 floats (divisible by 4)

// EMA coefficients: 1-exp(-0.016/0.005), 1-exp(-0.016/0.05)
#define ACF 0.9592377960216338f
#define RCF 0.27385096292630914f

// ---------------------------------------------------------------- prep
// Discovers filterbank sparsity at runtime:
//  - per-f: <=2 nonzero mels (triangular filters overlap at most 2x),
//    normalized by column sum (fb_norm), packed as float4 {w0,w1,m0,m1}
//  - per-m: contiguous support [fs, fs+len), weights stored TRANSPOSED
//    t_wm[i*64+m] so kernel-1 LDS reads are stride-1 across lanes (no
//    32-way bank conflict from a [m][i] layout).
__global__ void wdrc_prep(const float* __restrict__ fb,
                          float4* __restrict__ t_tab,
                          int* __restrict__ t_fs,
                          float* __restrict__ t_wm) {
    int tid = threadIdx.x;
    for (int f = tid; f < F_; f += blockDim.x) {
        float s = 0.f; int c = 0; int i0 = 0, i1 = 0; float v0 = 0.f, v1 = 0.f;
        for (int m = 0; m < M_; ++m) {
            float v = fb[m*F_ + f];
            s += v;
            if (v > 0.f) {
                if (c == 0) { i0 = m; v0 = v; }
                else if (c == 1) { i1 = m; v1 = v; }
                ++c;
            }
        }
        float inv = 1.0f / (s + 1e-8f);
        float w0 = v0*inv, w1 = v1*inv;
        if (c == 0) { i0 = 0; i1 = 0; w0 = 0.f; w1 = 0.f; }
        else if (c == 1) { i1 = i0; w1 = 0.f; }
        t_tab[f] = make_float4(w0, w1, __int_as_float(i0), __int_as_float(i1));
    }
    if (tid < M_) {
        int m = tid, lo = -1, hi = -1;
        for (int f = 0; f < F_; ++f)
            if (fb[m*F_ + f] > 0.f) { if (lo < 0) lo = f; hi = f; }
        int fs  = (lo < 0) ? 0 : lo;
        int len = (lo < 0) ? 0 : (hi - lo + 1);
        if (len > MAXSUP) len = MAXSUP;   // structurally ~21 max
        t_fs[m] = fs;
        for (int i = 0; i < MAXSUP; ++i)
            t_wm[i*M_ + m] = (i < len) ? fb[m*F_ + fs + i] : 0.f;
    }
}

// ---------------------------------------------------------------- mel + log10
// Block handles 32 contiguous flat rows (32*257 = 8224 floats, 16B-aligned
// tile starts since 8224 % 4 == 0). Stage tile in LDS via float4, then
// lane m gathers its contiguous support (zero-padded weights -> branchless).
__global__ __launch_bounds__(256) void wdrc_mel(const float* __restrict__ x,
                                                float* __restrict__ xdb,
                                                const int* __restrict__ t_fs,
                                                const float* __restrict__ t_wm) {
    __shared__ float xs[TILE_E + MAXSUP];   // pad so fs+i never reads OOB
    __shared__ float wms[MAXSUP*M_];        // transposed [i][m]
    __shared__ int   fss[M_];
    int tid = threadIdx.x;
    int r0  = blockIdx.x * TILE_R;

    const float4* src4 = (const float4*)(x + (size_t)r0 * F_);
    float4* dst4 = (float4*)xs;
    #pragma unroll
    for (int k = 0; k < 9; ++k) {           // ceil(2056/256)
        int i = tid + k*256;
        if (i < TILE_E/4) dst4[i] = src4[i];
    }
    if (tid < MAXSUP) xs[TILE_E + tid] = 0.f;
    for (int i = tid; i < MAXSUP*M_; i += 256) wms[i] = t_wm[i];
    if (tid < M_) fss[tid] = t_fs[tid];
    __syncthreads();

    int w = tid >> 6, m = tid & 63;
    int fs = fss[m];
    #pragma unroll
    for (int rr = w; rr < TILE_R; rr += 4) {
        const float* row = &xs[rr*F_ + fs];
        float acc = 0.f;
        #pragma unroll
        for (int i = 0; i < MAXSUP; ++i) {
            float v = row[i];
            acc = fmaf(v*v, wms[i*M_ + m], acc);
        }
        // 10*log10(p + 1e-8) = 10*log10(2) * log2(p + 1e-8)
        xdb[(size_t)(r0 + rr)*M_ + m] = 3.0102999566398120f * log2f(acc + 1e-8f);
    }
}

// ---------------------------------------------------------------- scan + compress + limit + gain
// One wave per (batch, chunk); lane = mel. Chunked EMA with 96-step warmup
// (the recurrence contracts by <=0.7262/step, so init error is ~1e-12 after
// warmup). 8-deep double-buffered prefetch: load addresses don't depend on
// the recurrence, so next block's loads are issued before computing current.
__global__ __launch_bounds__(256) void wdrc_scan(const float* __restrict__ xdb,
                                                 float* __restrict__ gl) {
    int tid = threadIdx.x;
    int wid = blockIdx.x * 4 + (tid >> 6);
    int m   = tid & 63;
    int b   = wid / CHUNKS;
    int c   = wid - b*CHUNKS;
    int ts  = c * CLEN, te = ts + CLEN;
    int tw  = ts - WARM; if (tw < 0) tw = 0;
    const size_t rowb = (size_t)b * T_;

    const float ac1 = 1.0f - ACF, rc1 = 1.0f - RCF;
    const float y2v   = 45.0f + 5.0f/3.0f;
    const float slope = (y2v - 50.0f) * 0.1f;

    float y = 0.f;
    float cur[8], nxt[8];
    #pragma unroll
    for (int i = 0; i < 8; ++i) {
        int t = tw + i; if (t >= te) t = te - 1;
        cur[i] = xdb[(rowb + t)*M_ + m];
    }
    for (int tb = tw; tb < te; tb += 8) {
        #pragma unroll
        for (int i = 0; i < 8; ++i) {
            int t = tb + 8 + i; if (t >= te) t = te - 1;
            nxt[i] = xdb[(rowb + t)*M_ + m];
        }
        #pragma unroll
        for (int i = 0; i < 8; ++i) {
            int t = tb + i;
            if (t < te) {                       // wave-uniform
                float xv = cur[i];
                float d  = xv - y;
                bool  up = d > 0.f;
                float a  = up ? ACF : RCF;
                float b1 = up ? ac1 : rc1;
                y = fmaf(a, xv, b1 * y);        // alpha*x + (1-alpha)*y
                if (t >= ts) {                  // wave-uniform: skip in warmup
                    float xG = y;
                    // soft-knee compressor (strict inequalities as in ref)
                    float yG;
                    if      (xG < 40.0f) yG = xG + 10.0f;
                    else if (xG > 50.0f) yG = fmaf(xG - 45.0f, 0.3333333333333333f, 45.0f);
                    else                 yG = fmaf(xG - 40.0f, slope, 50.0f);
                    // limiter
                    float xGc = yG;
                    float yL  = (xGc > 95.0f) ? 90.0f : xGc;
                    float ad  = fabsf(xGc - 90.0f);
                    if (ad < 5.0f) { float u = xGc - 85.0f; yL = xGc - u*u*0.05f; }
                    // gain_lin = 10^((yL - xG)/20) = exp2((yL-xG)*log2(10)/20)
                    float gd = yL - xG;
                    gl[(rowb + t)*M_ + m] = exp2f(gd * 0.16609640474436813f);
                }
            }
        }
        #pragma unroll
        for (int i = 0; i < 8; ++i) cur[i] = nxt[i];
    }
}

// ---------------------------------------------------------------- apply
// out = x * (sum over <=2 mels of gain_lin * fb_norm). float4 over the flat
// [B*T*F] array; per element: f = idx % 257, r = idx / 257 (magic-mul),
// one packed float4 LDS table read + 2 gain loads (L1/L2-hot).
#define NV4 (R_*F_/4)   // 6,168,000
__global__ __launch_bounds__(256) void wdrc_apply(const float* __restrict__ x,
                                                  const float* __restrict__ gl,
                                                  float* __restrict__ out,
                                                  const float4* __restrict__ t_tab) {
    __shared__ float4 stab[F_];
    int tid = threadIdx.x;
    for (int i = tid; i < F_; i += 256) stab[i] = t_tab[i];
    __syncthreads();

    const float4* x4 = (const float4*)x;
    float4* o4 = (float4*)out;
    int stride = gridDim.x * blockDim.x;
    for (int v = blockIdx.x*blockDim.x + tid; v < NV4; v += stride) {
        float4 xv = x4[v];
        float xi[4] = {xv.x, xv.y, xv.z, xv.w};
        float ov[4];
        int n0 = v*4;
        #pragma unroll
        for (int e = 0; e < 4; ++e) {
            int idx = n0 + e;
            int r = (int)((unsigned)idx / 257u);
            int f = idx - r*257;
            float4 tb = stab[f];
            const float* glr = gl + (size_t)r*M_;
            int m0 = __float_as_int(tb.z), m1 = __float_as_int(tb.w);
            float g = tb.x*glr[m0] + tb.y*glr[m1];
            ov[e] = xi[e] * g;
        }
        o4[v] = make_float4(ov[0], ov[1], ov[2], ov[3]);
    }
}

// ---------------------------------------------------------------- launch
extern "C" void kernel_launch(void* const* d_in, const int* in_sizes, int n_in,
                              void* d_out, int out_size, void* d_ws, size_t ws_size,
                              hipStream_t stream) {
    const float* x  = (const float*)d_in[0];
    const float* fb = (const float*)d_in[1];
    float* out = (float*)d_out;

    // workspace layout (all 16B-aligned: 6,144,000 floats = 24,576,000 B each)
    float*  xdb   = (float*)d_ws;
    float*  gl    = xdb + (size_t)R_*M_;
    float4* t_tab = (float4*)(gl + (size_t)R_*M_);
    int*    t_fs  = (int*)(t_tab + F_);
    float*  t_wm  = (float*)(t_fs + M_);

    size_t needed = (size_t)R_*M_*2*4 + F_*16 + M_*4 + MAXSUP*M_*4;
    if (ws_size < needed) return;  // insufficient scratch; fail loudly via validation

    wdrc_prep<<<1, 256, 0, stream>>>(fb, t_tab, t_fs, t_wm);
    wdrc_mel<<<R_/TILE_R, 256, 0, stream>>>(x, xdb, t_fs, t_wm);
    wdrc_scan<<<(B_*CHUNKS)/4, 256, 0, stream>>>(xdb, gl);
    wdrc_apply<<<2048, 256, 0, stream>>>(x, gl, out, t_tab);
}

// Round 6
// 294.836 us; speedup vs baseline: 1.0437x; 1.0437x over previous
//
#include <hip/hip_runtime.h>
#include <math.h>

#define B_ 16
#define T_ 6000
#define F_ 257
#define M_ 64
#define R_ (B_*T_)          // 96000 flat rows

// scan chunking
#define CHUNKS 48
#define CLEN   (T_/CHUNKS)  // 125
#define WARM   96           // worst-case decay 0.726^96 ~ 5e-14 -> below fp32 noise

// EMA coefficients: 1-exp(-0.016/0.005), 1-exp(-0.016/0.05)
#define ACF 0.9592377960216338f
#define RCF 0.27385096292630914f

// mel kernel tile
#define TILE_R 32
#define LSTR   260          // LDS row stride: 260 % 32 == 4 -> wave64 ds_read_b128 tiles banks cleanly
#define WSUP   32           // 4-aligned weight window (support <= 24 after alignment shift)

// ---------------------------------------------------------------- prep
// Builds, at runtime (no hardcoded filterbank):
//  - t_tab[f]  = {w0, w1, m0, m1}: per-frequency normalized weights (fb_norm
//    columns have <=2 nonzero, consecutive mels; all-zero cols 0/256 get
//    monotone-consistent dummy m0 so chunk offsets stay in [0,3])
//  - cw0/cw1/cmeta[j], j = chunk-slot (4*j mod 257 pattern repeats every 257
//    chunks): per-4-f weight vectors + {a = m0(f0), packed offs, fastflag}
//  - t_fs[m] = fa = (first support bin) & ~3 ; t_wm[i*64+m] = fb[m][fa+i]
//    (transposed, zero beyond f<257; zero weights outside support are exact
//    no-ops in the mel fma chain)
__global__ __launch_bounds__(256) void wdrc_prep(const float* __restrict__ fb,
    float4* __restrict__ t_tab, float4* __restrict__ cw0, float4* __restrict__ cw1,
    float4* __restrict__ cmeta, int* __restrict__ t_fs, float* __restrict__ t_wm)
{
    __shared__ float4 tabs[F_];
    __shared__ int    slo[4*M_];
    __shared__ int    sfa[M_];
    int tid = threadIdx.x;

    // P1: per-frequency column table
    for (int f = tid; f < F_; f += 256) {
        float s = 0.f; int c = 0; int i0 = 0, i1 = 0; float v0 = 0.f, v1 = 0.f;
        for (int m = 0; m < M_; ++m) {
            float v = fb[m*F_ + f];
            s += v;
            if (v > 0.f) { if (c==0){i0=m;v0=v;} else if (c==1){i1=m;v1=v;} ++c; }
        }
        float inv = 1.0f/(s + 1e-8f);
        float w0 = v0*inv, w1 = v1*inv;
        if (c == 0) { i0 = (f >= 128) ? 63 : 0; i1 = i0 + 1; w0 = 0.f; w1 = 0.f; }
        else if (c == 1) { i1 = i0 + 1; w1 = 0.f; }   // consecutive-mel convention
        float4 tv = make_float4(w0, w1, __int_as_float(i0), __int_as_float(i1));
        tabs[f] = tv; t_tab[f] = tv;
    }
    // P3a: per-mel first support bin, segmented over 4 waves
    {
        int m = tid & 63, seg = tid >> 6;
        int f0 = seg*65, f1 = f0 + 65; if (f1 > F_) f1 = F_;
        int lo = 0x7fffffff;
        for (int f = f0; f < f1; ++f)
            if (fb[m*F_ + f] > 0.f) { lo = f; break; }
        slo[seg*M_ + m] = lo;
    }
    __syncthreads();
    // P2: per-chunk-slot fast tables (reads tabs)
    for (int j = tid; j < F_; j += 256) {
        int f0 = 4*j; f0 -= 257*(f0/257);
        int fast = (f0 < 254);                 // straddling chunks -> slow path
        float4 tv0 = tabs[f0];
        int a = __float_as_int(tv0.z);
        float w0e[4], w1e[4]; int offp = 0;
        for (int e = 0; e < 4; ++e) {
            int fe = f0 + e; if (fe > 256) fe = 256;   // only hit on slow slots
            float4 t = tabs[fe];
            int off = __float_as_int(t.z) - a;
            if (off < 0) off = 0; if (off > 3) off = 3;
            offp |= off << (8*e);
            w0e[e] = t.x; w1e[e] = t.y;
        }
        cw0[j] = make_float4(w0e[0], w0e[1], w0e[2], w0e[3]);
        cw1[j] = make_float4(w1e[0], w1e[1], w1e[2], w1e[3]);
        cmeta[j] = make_float4(__int_as_float(a), __int_as_float(offp),
                               __int_as_float(fast), 0.f);
    }
    // P3b: combine segment minima -> fa
    if (tid < M_) {
        int lo = slo[tid];
        for (int s2 = 1; s2 < 4; ++s2) { int v = slo[s2*M_ + tid]; if (v < lo) lo = v; }
        if (lo == 0x7fffffff) lo = 0;
        int fa = lo & ~3;
        sfa[tid] = fa; t_fs[tid] = fa;
    }
    __syncthreads();
    // P3c: aligned-window weights, transposed [i][m]
    {
        int m = tid & 63;
        int fa = sfa[m];
        for (int i = tid >> 6; i < WSUP; i += 4) {
            int f = fa + i;
            t_wm[i*M_ + m] = (f < F_) ? fb[m*F_ + f] : 0.f;
        }
    }
}

// ---------------------------------------------------------------- mel + log10
// 32 rows/block staged as SQUARED values into LDS with stride-260 rows
// (260 % 32 == 4 -> b128 wave reads tile the 32 banks at the 8-cycle
// minimum). Lane = mel reads its 4-aligned 32-wide window as 8 ds_read_b128
// with weights held in 32 VGPRs. Zero-padded weights make the fa-shift and
// row-tail spill exact no-ops (fmaf(v, 0, acc) == acc).
__global__ __launch_bounds__(256) void wdrc_mel(const float* __restrict__ x,
    float* __restrict__ xdb, const int* __restrict__ t_fs, const float* __restrict__ t_wm)
{
    __shared__ __align__(16) float xs[TILE_R*LSTR + 64];
    __shared__ float wms[WSUP*M_];
    __shared__ int   fss[M_];
    int tid = threadIdx.x;
    size_t r0 = (size_t)blockIdx.x * TILE_R;

    for (int i = tid; i < WSUP*M_; i += 256) wms[i] = t_wm[i];
    if (tid < M_) fss[tid] = t_fs[tid];
    // zero row pads (cols 257..259) + 64-float tail guard (uninit LDS may be NaN)
    for (int i = tid; i < TILE_R*3 + 64; i += 256) {
        if (i < TILE_R*3) { int r = i/3; int c = i - 3*r; xs[r*LSTR + F_ + c] = 0.f; }
        else xs[TILE_R*LSTR + (i - TILE_R*3)] = 0.f;
    }
    // stage x^2 (tile base 32*257*4*bid bytes: 16B aligned)
    const float4* src4 = (const float4*)(x + r0*F_);
    for (int c = tid; c < TILE_R*F_/4; c += 256) {
        float4 v = src4[c];
        float vv[4] = {v.x*v.x, v.y*v.y, v.z*v.z, v.w*v.w};
        int g = 4*c;
        #pragma unroll
        for (int e = 0; e < 4; ++e) {
            int idx = g + e;
            int r = (int)((unsigned)idx / 257u);
            int f = idx - 257*r;
            xs[r*LSTR + f] = vv[e];
        }
    }
    __syncthreads();

    int m = tid & 63, w = tid >> 6;
    int fa = fss[m];
    float wr[WSUP];
    #pragma unroll
    for (int i = 0; i < WSUP; ++i) wr[i] = wms[i*M_ + m];   // stride-64: 2-way, free

    for (int rr = w; rr < TILE_R; rr += 4) {
        const float4* px = (const float4*)&xs[rr*LSTR + fa];  // 16B aligned: 260%4==0, fa%4==0
        float acc = 0.f;
        #pragma unroll
        for (int j = 0; j < 8; ++j) {
            float4 q = px[j];
            acc = fmaf(q.x, wr[4*j+0], acc);
            acc = fmaf(q.y, wr[4*j+1], acc);
            acc = fmaf(q.z, wr[4*j+2], acc);
            acc = fmaf(q.w, wr[4*j+3], acc);
        }
        xdb[(r0 + rr)*M_ + m] = 3.0102999566398120f * log2f(acc + 1e-8f);
    }
}

// ---------------------------------------------------------------- scan + compress + limit + gain
// Unchanged from the passing version (numerics preserved bit-for-bit).
__global__ __launch_bounds__(256) void wdrc_scan(const float* __restrict__ xdb,
                                                 float* __restrict__ gl) {
    int tid = threadIdx.x;
    int wid = blockIdx.x * 4 + (tid >> 6);
    int m   = tid & 63;
    int b   = wid / CHUNKS;
    int c   = wid - b*CHUNKS;
    int ts  = c * CLEN, te = ts + CLEN;
    int tw  = ts - WARM; if (tw < 0) tw = 0;
    const size_t rowb = (size_t)b * T_;

    const float ac1 = 1.0f - ACF, rc1 = 1.0f - RCF;
    const float y2v   = 45.0f + 5.0f/3.0f;
    const float slope = (y2v - 50.0f) * 0.1f;

    float y = 0.f;
    float cur[8], nxt[8];
    #pragma unroll
    for (int i = 0; i < 8; ++i) {
        int t = tw + i; if (t >= te) t = te - 1;
        cur[i] = xdb[(rowb + t)*M_ + m];
    }
    for (int tb = tw; tb < te; tb += 8) {
        #pragma unroll
        for (int i = 0; i < 8; ++i) {
            int t = tb + 8 + i; if (t >= te) t = te - 1;
            nxt[i] = xdb[(rowb + t)*M_ + m];
        }
        #pragma unroll
        for (int i = 0; i < 8; ++i) {
            int t = tb + i;
            if (t < te) {
                float xv = cur[i];
                float d  = xv - y;
                bool  up = d > 0.f;
                float a  = up ? ACF : RCF;
                float b1 = up ? ac1 : rc1;
                y = fmaf(a, xv, b1 * y);
                if (t >= ts) {
                    float xG = y;
                    float yG;
                    if      (xG < 40.0f) yG = xG + 10.0f;
                    else if (xG > 50.0f) yG = fmaf(xG - 45.0f, 0.3333333333333333f, 45.0f);
                    else                 yG = fmaf(xG - 40.0f, slope, 50.0f);
                    float xGc = yG;
                    float yL  = (xGc > 95.0f) ? 90.0f : xGc;
                    float ad  = fabsf(xGc - 90.0f);
                    if (ad < 5.0f) { float u = xGc - 85.0f; yL = xGc - u*u*0.05f; }
                    float gd = yL - xG;
                    gl[(rowb + t)*M_ + m] = exp2f(gd * 0.16609640474436813f);
                }
            }
        }
        #pragma unroll
        for (int i = 0; i < 8; ++i) cur[i] = nxt[i];
    }
}

// ---------------------------------------------------------------- apply
// Block = 32 rows. gl rows staged in LDS ([32][68], pad zeroed), chunk
// tables staged in LDS. Fast path per float4: m0 is monotone with <=1 step
// per f, so 4 consecutive f only need gl[a..a+4]: 5 ds_read_b32 + cndmask
// selects instead of 8 scalar global gathers. Chunks that straddle a row
// boundary (3 of 257) take the exec-masked per-element slow path.
__global__ __launch_bounds__(256) void wdrc_apply(const float* __restrict__ x,
    const float* __restrict__ gl, float* __restrict__ out,
    const float4* __restrict__ t_tab, const float4* __restrict__ cw0,
    const float4* __restrict__ cw1, const float4* __restrict__ cmeta)
{
    __shared__ __align__(16) float gls[32*68];
    __shared__ float4 sw0[F_], sw1[F_], sme[F_], stab[F_];
    int tid = threadIdx.x;
    size_t r0 = (size_t)blockIdx.x * 32;

    for (int i = tid; i < F_; i += 256) {
        sw0[i] = cw0[i]; sw1[i] = cw1[i]; sme[i] = cmeta[i]; stab[i] = t_tab[i];
    }
    const float4* g4 = (const float4*)(gl + r0*M_);
    for (int i = tid; i < 512; i += 256) {
        float4 v = g4[i];
        int r = i >> 4, c0 = (i & 15) << 2;
        *(float4*)&gls[r*68 + c0] = v;          // 68%4==0 -> 16B aligned
    }
    for (int i = tid; i < 128; i += 256) { int r = i >> 2; gls[r*68 + 64 + (i & 3)] = 0.f; }
    __syncthreads();

    const float4* x4 = (const float4*)(x + r0*F_);   // 32*257*4*bid: 16B aligned
    float4*       o4 = (float4*)(out + r0*F_);
    for (int i = tid; i < 2056; i += 256) {
        float4 xv = x4[i];
        int j = i - 257*(i/257);                 // chunk-slot (block base % 257 == 0)
        int r = (int)((unsigned)(4*i) / 257u);   // local row of f0
        float4 me = sme[j];
        float xe[4] = {xv.x, xv.y, xv.z, xv.w};
        float ov[4];
        if (__float_as_int(me.z)) {
            float4 w0 = sw0[j], w1 = sw1[j];
            int a    = __float_as_int(me.x);
            int offp = __float_as_int(me.y);
            const float* gr = &gls[r*68 + a];
            float g0 = gr[0], g1 = gr[1], g2 = gr[2], g3 = gr[3], gX = gr[4];
            float w0a[4] = {w0.x, w0.y, w0.z, w0.w};
            float w1a[4] = {w1.x, w1.y, w1.z, w1.w};
            #pragma unroll
            for (int e = 0; e < 4; ++e) {
                int off = (offp >> (8*e)) & 3;
                float ge  = off==0 ? g0 : off==1 ? g1 : off==2 ? g2 : g3;
                float ge1 = off==0 ? g1 : off==1 ? g2 : off==2 ? g3 : gX;
                float g = w0a[e]*ge + w1a[e]*ge1;
                ov[e] = xe[e]*g;
            }
        } else {
            int base = 4*i;
            #pragma unroll
            for (int e = 0; e < 4; ++e) {
                int idx = base + e;
                int rr = (int)((unsigned)idx / 257u);
                int f  = idx - 257*rr;
                float4 tb = stab[f];
                int m0 = __float_as_int(tb.z), m1 = __float_as_int(tb.w);
                float g = tb.x*gls[rr*68 + m0] + tb.y*gls[rr*68 + m1];
                ov[e] = xe[e]*g;
            }
        }
        o4[i] = make_float4(ov[0], ov[1], ov[2], ov[3]);
    }
}

// ---------------------------------------------------------------- launch
extern "C" void kernel_launch(void* const* d_in, const int* in_sizes, int n_in,
                              void* d_out, int out_size, void* d_ws, size_t ws_size,
                              hipStream_t stream) {
    const float* x  = (const float*)d_in[0];
    const float* fb = (const float*)d_in[1];
    float* out = (float*)d_out;

    // workspace layout (d_ws is 256B-aligned; all sections stay 16B-aligned)
    float*  xdb   = (float*)d_ws;                       // R_*M_ f32
    float*  gl    = xdb + (size_t)R_*M_;                // R_*M_ f32
    float4* t_tab = (float4*)(gl + (size_t)R_*M_);      // F_ float4
    float4* cw0   = t_tab + F_;                         // F_ float4
    float4* cw1   = cw0 + F_;                           // F_ float4
    float4* cmeta = cw1 + F_;                           // F_ float4
    int*    t_fs  = (int*)(cmeta + F_);                 // M_ int
    float*  t_wm  = (float*)(t_fs + M_);                // WSUP*M_ f32

    size_t needed = (size_t)R_*M_*2*4 + (size_t)F_*16*4 + M_*4 + (size_t)WSUP*M_*4;
    if (ws_size < needed) return;

    wdrc_prep<<<1, 256, 0, stream>>>(fb, t_tab, cw0, cw1, cmeta, t_fs, t_wm);
    wdrc_mel<<<R_/TILE_R, 256, 0, stream>>>(x, xdb, t_fs, t_wm);
    wdrc_scan<<<(B_*CHUNKS)/4, 256, 0, stream>>>(xdb, gl);
    wdrc_apply<<<R_/32, 256, 0, stream>>>(x, gl, out, t_tab, cw0, cw1, cmeta);
}

// Round 9
// 292.139 us; speedup vs baseline: 1.0533x; 1.0092x over previous
//
#include <hip/hip_runtime.h>
#include <math.h>

#define B_ 16
#define T_ 6000
#define F_ 257
#define M_ 64
#define R_ (B_*T_)          // 96000 flat rows

// scan chunking
#define CHUNKS 48
#define CLEN   (T_/CHUNKS)  // 125
#define WARM   96           // worst-case decay 0.726^96 ~ 5e-14 -> below fp32 noise

// EMA coefficients: 1-exp(-0.016/0.005), 1-exp(-0.016/0.05)
#define ACF 0.9592377960216338f
#define RCF 0.27385096292630914f

// mel kernel tile
#define TILE_R 32
#define LSTR   260          // LDS row stride: 260 % 32 == 4
#define WSUP   32           // 4-aligned weight window (support <= 24 after alignment shift)

// ---------------------------------------------------------------- prep
// Runtime-discovered filterbank structure (no hardcoding):
//  - t_tab[f] = {w0,w1,m0,m1} per-frequency normalized column (<=2 nonzero,
//    consecutive mels; zero cols get monotone-consistent dummy indices)
//  - cw0/cw1/cmeta[j]: per-float4-chunk fast-path tables for apply
//  - t_fs[m] = fa = first-support-bin & ~3 ; t_wm[m*32+i] = fb[m][fa+i]
//    (PER-MEL CONTIGUOUS layout so mel kernel lane m loads its 32 weights
//    as 8 global dwordx4, L1-hot; zero-padded -> fmaf no-ops)
__global__ __launch_bounds__(256) void wdrc_prep(const float* __restrict__ fb,
    float4* __restrict__ t_tab, float4* __restrict__ cw0, float4* __restrict__ cw1,
    float4* __restrict__ cmeta, int* __restrict__ t_fs, float* __restrict__ t_wm)
{
    __shared__ float4 tabs[F_];
    __shared__ int    slo[4*M_];
    __shared__ int    sfa[M_];
    int tid = threadIdx.x;

    // P1: per-frequency column table
    for (int f = tid; f < F_; f += 256) {
        float s = 0.f; int c = 0; int i0 = 0, i1 = 0; float v0 = 0.f, v1 = 0.f;
        for (int m = 0; m < M_; ++m) {
            float v = fb[m*F_ + f];
            s += v;
            if (v > 0.f) { if (c==0){i0=m;v0=v;} else if (c==1){i1=m;v1=v;} ++c; }
        }
        float inv = 1.0f/(s + 1e-8f);
        float w0 = v0*inv, w1 = v1*inv;
        if (c == 0) { i0 = (f >= 128) ? 63 : 0; i1 = i0 + 1; w0 = 0.f; w1 = 0.f; }
        else if (c == 1) { i1 = i0 + 1; w1 = 0.f; }   // consecutive-mel convention
        float4 tv = make_float4(w0, w1, __int_as_float(i0), __int_as_float(i1));
        tabs[f] = tv; t_tab[f] = tv;
    }
    // P3a: per-mel first support bin, segmented over 4 waves
    {
        int m = tid & 63, seg = tid >> 6;
        int f0 = seg*65, f1 = f0 + 65; if (f1 > F_) f1 = F_;
        int lo = 0x7fffffff;
        for (int f = f0; f < f1; ++f)
            if (fb[m*F_ + f] > 0.f) { lo = f; break; }
        slo[seg*M_ + m] = lo;
    }
    __syncthreads();
    // P2: per-chunk-slot fast tables (reads tabs)
    for (int j = tid; j < F_; j += 256) {
        int f0 = 4*j; f0 -= 257*(f0/257);
        int fast = (f0 < 254);                 // straddling chunks -> slow path
        float4 tv0 = tabs[f0];
        int a = __float_as_int(tv0.z);
        float w0e[4], w1e[4]; int offp = 0;
        for (int e = 0; e < 4; ++e) {
            int fe = f0 + e; if (fe > 256) fe = 256;   // only hit on slow slots
            float4 t = tabs[fe];
            int off = __float_as_int(t.z) - a;
            if (off < 0) off = 0; if (off > 3) off = 3;
            offp |= off << (8*e);
            w0e[e] = t.x; w1e[e] = t.y;
        }
        cw0[j] = make_float4(w0e[0], w0e[1], w0e[2], w0e[3]);
        cw1[j] = make_float4(w1e[0], w1e[1], w1e[2], w1e[3]);
        cmeta[j] = make_float4(__int_as_float(a), __int_as_float(offp),
                               __int_as_float(fast), 0.f);
    }
    // P3b: combine segment minima -> fa
    if (tid < M_) {
        int lo = slo[tid];
        for (int s2 = 1; s2 < 4; ++s2) { int v = slo[s2*M_ + tid]; if (v < lo) lo = v; }
        if (lo == 0x7fffffff) lo = 0;
        int fa = lo & ~3;
        sfa[tid] = fa; t_fs[tid] = fa;
    }
    __syncthreads();
    // P3c: aligned-window weights, per-mel contiguous [m][i]
    {
        int m = tid & 63;
        int fa = sfa[m];
        for (int i = tid >> 6; i < WSUP; i += 4) {
            int f = fa + i;
            t_wm[m*WSUP + i] = (f < F_) ? fb[m*F_ + f] : 0.f;
        }
    }
}

// ---------------------------------------------------------------- mel + log10
// 32 rows/block staged as SQUARED values into LDS (stride-260 rows). Lane =
// mel. KEY FIX vs prev round: per-lane ROTATED read order. fa is 4-aligned,
// so fa mod 32 takes only 8 values -> all lanes in the same class hit one
// bank per b128 phase (~4-8-way conflict). Reading float4 j' = (jj+m)&7
// makes the bank-class (fa/4 + m + jj) mod 8; fa(m)/4 + m is strictly
// increasing in m, so consecutive lanes land in distinct classes -> ~2
// lanes/bank = free. Weights are pre-rotated into registers (static reg
// indices) straight from global t_wm[m*32+..] (L1-hot, no LDS copy ->
// LDS = 33.5 KB -> 4 blocks/CU instead of 3).
__global__ __launch_bounds__(256) void wdrc_mel(const float* __restrict__ x,
    float* __restrict__ xdb, const int* __restrict__ t_fs, const float* __restrict__ t_wm)
{
    __shared__ __align__(16) float xs[TILE_R*LSTR + 64];
    int tid = threadIdx.x;
    size_t r0 = (size_t)blockIdx.x * TILE_R;

    // zero row pads (cols 257..259) + tail guard (window spill reads must be finite)
    for (int i = tid; i < TILE_R*3 + 64; i += 256) {
        if (i < TILE_R*3) { int r = i/3; int c = i - 3*r; xs[r*LSTR + F_ + c] = 0.f; }
        else xs[TILE_R*LSTR + (i - TILE_R*3)] = 0.f;
    }
    // stage x^2 (tile base 32*257*4*bid bytes: 16B aligned)
    const float4* src4 = (const float4*)(x + r0*F_);
    for (int c = tid; c < TILE_R*F_/4; c += 256) {
        float4 v = src4[c];
        float vv[4] = {v.x*v.x, v.y*v.y, v.z*v.z, v.w*v.w};
        int g = 4*c;
        #pragma unroll
        for (int e = 0; e < 4; ++e) {
            int idx = g + e;
            int r = (int)((unsigned)idx / 257u);
            int f = idx - 257*r;
            xs[r*LSTR + f] = vv[e];
        }
    }

    int m = tid & 63, w = tid >> 6;
    int rot = m & 7;
    int fa  = t_fs[m];                       // coalesced global scalar load
    // pre-rotated weights: wz[4*jj+e] == fb-window float4 #((jj+rot)&7), elem e
    float wz[WSUP];
    const float4* wm4 = (const float4*)(t_wm + m*WSUP);
    #pragma unroll
    for (int jj = 0; jj < 8; ++jj) {
        float4 qw = wm4[(jj + rot) & 7];     // runtime-addressed global load, L1-hot
        wz[4*jj+0] = qw.x; wz[4*jj+1] = qw.y; wz[4*jj+2] = qw.z; wz[4*jj+3] = qw.w;
    }
    __syncthreads();

    for (int rr = w; rr < TILE_R; rr += 4) {
        const float* base = &xs[rr*LSTR + fa];   // 16B aligned: 260%4==0, fa%4==0
        float acc = 0.f;
        #pragma unroll
        for (int jj = 0; jj < 8; ++jj) {
            const float4 q = *(const float4*)(base + 4*((jj + rot) & 7));
            acc = fmaf(q.x, wz[4*jj+0], acc);
            acc = fmaf(q.y, wz[4*jj+1], acc);
            acc = fmaf(q.z, wz[4*jj+2], acc);
            acc = fmaf(q.w, wz[4*jj+3], acc);
        }
        xdb[(r0 + rr)*M_ + m] = 3.0102999566398120f * log2f(acc + 1e-8f);
    }
}

// ---------------------------------------------------------------- scan + compress + limit + gain
// Unchanged (passing numerics preserved).
__global__ __launch_bounds__(256) void wdrc_scan(const float* __restrict__ xdb,
                                                 float* __restrict__ gl) {
    int tid = threadIdx.x;
    int wid = blockIdx.x * 4 + (tid >> 6);
    int m   = tid & 63;
    int b   = wid / CHUNKS;
    int c   = wid - b*CHUNKS;
    int ts  = c * CLEN, te = ts + CLEN;
    int tw  = ts - WARM; if (tw < 0) tw = 0;
    const size_t rowb = (size_t)b * T_;

    const float ac1 = 1.0f - ACF, rc1 = 1.0f - RCF;
    const float y2v   = 45.0f + 5.0f/3.0f;
    const float slope = (y2v - 50.0f) * 0.1f;

    float y = 0.f;
    float cur[8], nxt[8];
    #pragma unroll
    for (int i = 0; i < 8; ++i) {
        int t = tw + i; if (t >= te) t = te - 1;
        cur[i] = xdb[(rowb + t)*M_ + m];
    }
    for (int tb = tw; tb < te; tb += 8) {
        #pragma unroll
        for (int i = 0; i < 8; ++i) {
            int t = tb + 8 + i; if (t >= te) t = te - 1;
            nxt[i] = xdb[(rowb + t)*M_ + m];
        }
        #pragma unroll
        for (int i = 0; i < 8; ++i) {
            int t = tb + i;
            if (t < te) {
                float xv = cur[i];
                float d  = xv - y;
                bool  up = d > 0.f;
                float a  = up ? ACF : RCF;
                float b1 = up ? ac1 : rc1;
                y = fmaf(a, xv, b1 * y);
                if (t >= ts) {
                    float xG = y;
                    float yG;
                    if      (xG < 40.0f) yG = xG + 10.0f;
                    else if (xG > 50.0f) yG = fmaf(xG - 45.0f, 0.3333333333333333f, 45.0f);
                    else                 yG = fmaf(xG - 40.0f, slope, 50.0f);
                    float xGc = yG;
                    float yL  = (xGc > 95.0f) ? 90.0f : xGc;
                    float ad  = fabsf(xGc - 90.0f);
                    if (ad < 5.0f) { float u = xGc - 85.0f; yL = xGc - u*u*0.05f; }
                    float gd = yL - xG;
                    gl[(rowb + t)*M_ + m] = exp2f(gd * 0.16609640474436813f);
                }
            }
        }
        #pragma unroll
        for (int i = 0; i < 8; ++i) cur[i] = nxt[i];
    }
}

// ---------------------------------------------------------------- apply
// Unchanged (passing). Block = 32 rows; gl rows + chunk tables in LDS;
// monotone fast path: 5 LDS b32 per float4 instead of 8 global gathers.
__global__ __launch_bounds__(256) void wdrc_apply(const float* __restrict__ x,
    const float* __restrict__ gl, float* __restrict__ out,
    const float4* __restrict__ t_tab, const float4* __restrict__ cw0,
    const float4* __restrict__ cw1, const float4* __restrict__ cmeta)
{
    __shared__ __align__(16) float gls[32*68];
    __shared__ float4 sw0[F_], sw1[F_], sme[F_], stab[F_];
    int tid = threadIdx.x;
    size_t r0 = (size_t)blockIdx.x * 32;

    for (int i = tid; i < F_; i += 256) {
        sw0[i] = cw0[i]; sw1[i] = cw1[i]; sme[i] = cmeta[i]; stab[i] = t_tab[i];
    }
    const float4* g4 = (const float4*)(gl + r0*M_);
    for (int i = tid; i < 512; i += 256) {
        float4 v = g4[i];
        int r = i >> 4, c0 = (i & 15) << 2;
        *(float4*)&gls[r*68 + c0] = v;          // 68%4==0 -> 16B aligned
    }
    for (int i = tid; i < 128; i += 256) { int r = i >> 2; gls[r*68 + 64 + (i & 3)] = 0.f; }
    __syncthreads();

    const float4* x4 = (const float4*)(x + r0*F_);   // 32*257*4*bid: 16B aligned
    float4*       o4 = (float4*)(out + r0*F_);
    for (int i = tid; i < 2056; i += 256) {
        float4 xv = x4[i];
        int j = i - 257*(i/257);                 // chunk-slot (block base % 257 == 0)
        int r = (int)((unsigned)(4*i) / 257u);   // local row of f0
        float4 me = sme[j];
        float xe[4] = {xv.x, xv.y, xv.z, xv.w};
        float ov[4];
        if (__float_as_int(me.z)) {
            float4 w0 = sw0[j], w1 = sw1[j];
            int a    = __float_as_int(me.x);
            int offp = __float_as_int(me.y);
            const float* gr = &gls[r*68 + a];
            float g0 = gr[0], g1 = gr[1], g2 = gr[2], g3 = gr[3], gX = gr[4];
            float w0a[4] = {w0.x, w0.y, w0.z, w0.w};
            float w1a[4] = {w1.x, w1.y, w1.z, w1.w};
            #pragma unroll
            for (int e = 0; e < 4; ++e) {
                int off = (offp >> (8*e)) & 3;
                float ge  = off==0 ? g0 : off==1 ? g1 : off==2 ? g2 : g3;
                float ge1 = off==0 ? g1 : off==1 ? g2 : off==2 ? g3 : gX;
                float g = w0a[e]*ge + w1a[e]*ge1;
                ov[e] = xe[e]*g;
            }
        } else {
            int base = 4*i;
            #pragma unroll
            for (int e = 0; e < 4; ++e) {
                int idx = base + e;
                int rr = (int)((unsigned)idx / 257u);
                int f  = idx - 257*rr;
                float4 tb = stab[f];
                int m0 = __float_as_int(tb.z), m1 = __float_as_int(tb.w);
                float g = tb.x*gls[rr*68 + m0] + tb.y*gls[rr*68 + m1];
                ov[e] = xe[e]*g;
            }
        }
        o4[i] = make_float4(ov[0], ov[1], ov[2], ov[3]);
    }
}

// ---------------------------------------------------------------- launch
extern "C" void kernel_launch(void* const* d_in, const int* in_sizes, int n_in,
                              void* d_out, int out_size, void* d_ws, size_t ws_size,
                              hipStream_t stream) {
    const float* x  = (const float*)d_in[0];
    const float* fb = (const float*)d_in[1];
    float* out = (float*)d_out;

    // workspace layout (d_ws is 256B-aligned; all sections stay 16B-aligned)
    float*  xdb   = (float*)d_ws;                       // R_*M_ f32
    float*  gl    = xdb + (size_t)R_*M_;                // R_*M_ f32
    float4* t_tab = (float4*)(gl + (size_t)R_*M_);      // F_ float4
    float4* cw0   = t_tab + F_;                         // F_ float4
    float4* cw1   = cw0 + F_;                           // F_ float4
    float4* cmeta = cw1 + F_;                           // F_ float4
    int*    t_fs  = (int*)(cmeta + F_);                 // M_ int
    float*  t_wm  = (float*)(t_fs + M_);                // M_*WSUP f32 [m][i]

    size_t needed = (size_t)R_*M_*2*4 + (size_t)F_*16*4 + M_*4 + (size_t)WSUP*M_*4;
    if (ws_size < needed) return;

    wdrc_prep<<<1, 256, 0, stream>>>(fb, t_tab, cw0, cw1, cmeta, t_fs, t_wm);
    wdrc_mel<<<R_/TILE_R, 256, 0, stream>>>(x, xdb, t_fs, t_wm);
    wdrc_scan<<<(B_*CHUNKS)/4, 256, 0, stream>>>(xdb, gl);
    wdrc_apply<<<R_/32, 256, 0, stream>>>(x, gl, out, t_tab, cw0, cw1, cmeta);
}